// Round 4
// baseline (278.642 us; speedup 1.0000x reference)
//
#include <hip/hip_runtime.h>

// LearnedQueryAttention: B=8, L=4096, KD=512, ED=1024, H=8. All I/O fp32.
// Raw-reshape semantics: head h owns the contiguous flat slab
// f = h*(L+1)*(C/H) + row*(C/H) + d of per-batch [X_flat | bias]; only
// f >= L*C touches the bias token.
#define BATCH 8
#define LSEQ  4096
#define LP    4097
#define KDIM  512
#define EDIM  1024
#define NH    8
#define DK    64
#define DV    128
#define NG    64          // B*H groups
#define SSTR  4112        // padded per-group score stride (floats)
#define NCK   8           // score-stage chunks per group
#define RCK   513
#define NC    16          // value-stage chunks per group
#define RC    257
#define LN_EPS 1e-5f

// Native vector type: __builtin_nontemporal_load requires scalar/native-vector
// pointee (HIP_vector_type float4 is rejected). Same 16B layout as float4.
typedef float floatx4 __attribute__((ext_vector_type(4)));

// ---------------------------------------------------------------------------
// Kernel 1: t[g][row] = dot64(Q[h], Kcat) * w[h][row] + b[h][row], plus
// per-chunk online-softmax stats (m, z). Grid (8, 64), 256 thr.
// ---------------------------------------------------------------------------
__global__ __launch_bounds__(256) void lqa_scores_kernel(
    const float* __restrict__ keys, const float* __restrict__ k_bias,
    const float* __restrict__ query, const float* __restrict__ sw,
    const float* __restrict__ sb, float* __restrict__ p,
    float2* __restrict__ stats)
{
    const int chunk = blockIdx.x;            // 0..7
    const int g = blockIdx.y;                // 0..63
    const int b = g >> 3, h = g & 7;
    const int t = threadIdx.x;
    const int lane16 = t & 15;
    const int d0 = lane16 * 4;

    const floatx4 q = *reinterpret_cast<const floatx4*>(query + h * DK + d0);
    const float* kp = keys + (long long)b * (LSEQ * KDIM);
    const int fhead = h * (LP * DK);
    const int row0 = chunk * RCK;
    const int row_end = min(LP, row0 + RCK);
    float* prow = p + (long long)g * SSTR;
    const float* w = sw + h * LP;
    const float* bb = sb + h * LP;

    float mloc = -1e30f, zloc = 0.f;
    for (int row = row0 + (t >> 4); row < row_end; row += 16) {
        const int f = fhead + row * DK + d0;
        floatx4 k;
        if (f < LSEQ * KDIM)
            k = __builtin_nontemporal_load(reinterpret_cast<const floatx4*>(kp + f));
        else
            k = *reinterpret_cast<const floatx4*>(k_bias + (f - LSEQ * KDIM));
        float s = q.x * k.x + q.y * k.y + q.z * k.z + q.w * k.w;
        s += __shfl_xor(s, 1);
        s += __shfl_xor(s, 2);
        s += __shfl_xor(s, 4);
        s += __shfl_xor(s, 8);
        if (lane16 == 0) {
            const float tv = s * w[row] + bb[row];
            prow[row] = tv;
            if (tv > mloc) { zloc = zloc * __expf(mloc - tv) + 1.f; mloc = tv; }
            else            zloc += __expf(tv - mloc);
        }
    }

    __shared__ float mred[256], zred[256];
    mred[t] = mloc; zred[t] = zloc;
    for (int off = 128; off > 0; off >>= 1) {
        __syncthreads();
        if (t < off) {
            const float m1 = mred[t], z1 = zred[t];
            const float m2 = mred[t + off], z2 = zred[t + off];
            const float m = fmaxf(m1, m2);
            mred[t] = m;
            zred[t] = z1 * __expf(m1 - m) + z2 * __expf(m2 - m);
        }
    }
    if (t == 0) stats[g * NCK + chunk] = make_float2(mred[0], zred[0]);
}

// ---------------------------------------------------------------------------
// Kernel 2: combine chunk stats -> (m, Z); stage softmax weights
// exp(t-m)/Z for this value-chunk in LDS; accumulate A partials over Vcat.
// Grid (16, 64), 256 thr; 32 lanes per row (float4), 8 row subsets.
// Output partials are fully normalized.
// ---------------------------------------------------------------------------
__global__ __launch_bounds__(256) void lqa_av_kernel(
    const float* __restrict__ values, const float* __restrict__ v_bias,
    const float* __restrict__ p, const float2* __restrict__ stats,
    float* __restrict__ partials)
{
    const int chunk = blockIdx.x;            // 0..15
    const int g = blockIdx.y;                // 0..63
    const int b = g >> 3, h = g & 7;
    const int t = threadIdx.x;
    const int srow = t >> 5;                 // 0..7
    const int d0 = (t & 31) * 4;             // 0..124

    // global softmax stats (redundant per thread; 8 broadcast float2 loads)
    float m = -1e30f, Z = 0.f;
#pragma unroll
    for (int c = 0; c < NCK; ++c) {
        const float2 s = stats[g * NCK + c];
        const float mn = fmaxf(m, s.x);
        Z = Z * __expf(m - mn) + s.y * __expf(s.x - mn);
        m = mn;
    }
    const float rinv = 1.f / Z;

    const float* vp = values + (long long)b * (LSEQ * EDIM);
    const int fhead = h * (LP * DV);
    const float* prow = p + (long long)g * SSTR;
    const int row0 = chunk * RC;
    const int nrows = min(LP, row0 + RC) - row0;

    __shared__ float pw[RC];
    for (int r = t; r < nrows; r += 256)
        pw[r] = __expf(prow[row0 + r] - m) * rinv;
    __syncthreads();

    float acc[4] = {0.f, 0.f, 0.f, 0.f};
    for (int r = srow; r < nrows; r += 8) {
        const float wgt = pw[r];
        const int f = fhead + (row0 + r) * DV + d0;
        floatx4 v;
        if (f < LSEQ * EDIM)
            v = __builtin_nontemporal_load(reinterpret_cast<const floatx4*>(vp + f));
        else
            v = *reinterpret_cast<const floatx4*>(v_bias + (f - LSEQ * EDIM));
        acc[0] += wgt * v.x; acc[1] += wgt * v.y;
        acc[2] += wgt * v.z; acc[3] += wgt * v.w;
    }

    __shared__ float red[256 * 4];
#pragma unroll
    for (int j = 0; j < 4; ++j) red[t * 4 + j] = acc[j];
    for (int off = 128; off >= 32; off >>= 1) {
        __syncthreads();
        if (t < off) {
#pragma unroll
            for (int j = 0; j < 4; ++j) red[t * 4 + j] += red[(t + off) * 4 + j];
        }
    }
    __syncthreads();
    if (t < 32) {
        float* dst = partials + ((long long)(g * NC + chunk)) * DV + t * 4;
#pragma unroll
        for (int j = 0; j < 4; ++j) dst[j] = red[t * 4 + j];
    }
}

// ---------------------------------------------------------------------------
// Kernel 3: reduce chunk partials, LayerNorm over 1024 dims, gamma/beta.
// One block per batch.
// ---------------------------------------------------------------------------
__global__ __launch_bounds__(256) void lqa_ln_kernel(
    const float* __restrict__ partials, const float* __restrict__ gamma,
    const float* __restrict__ beta, float* __restrict__ out)
{
    const int b = blockIdx.x;
    const int t = threadIdx.x;
    __shared__ float r1[256], r2[256];

    float a[4];
    float s1 = 0.f, s2 = 0.f;
#pragma unroll
    for (int i = 0; i < 4; ++i) {
        const int e = t + i * 256;
        const int h = e >> 7, d = e & 127;
        const float* src = partials + ((long long)((b * NH + h) * NC)) * DV + d;
        float sum = 0.f;
#pragma unroll
        for (int c = 0; c < NC; ++c) sum += src[c * DV];
        a[i] = sum;
        s1 += sum;
        s2 += sum * sum;
    }
    r1[t] = s1; r2[t] = s2; __syncthreads();
    for (int off = 128; off > 0; off >>= 1) {
        if (t < off) { r1[t] += r1[t + off]; r2[t] += r2[t + off]; }
        __syncthreads();
    }
    const float mean = r1[0] * (1.0f / EDIM);
    const float var = r2[0] * (1.0f / EDIM) - mean * mean;
    const float inv = rsqrtf(var + LN_EPS);
#pragma unroll
    for (int i = 0; i < 4; ++i) {
        const int e = t + i * 256;
        out[(long long)b * EDIM + e] = (a[i] - mean) * inv * gamma[e] + beta[e];
    }
}

// ---------------------------------------------------------------------------
extern "C" void kernel_launch(void* const* d_in, const int* in_sizes, int n_in,
                              void* d_out, int out_size, void* d_ws, size_t ws_size,
                              hipStream_t stream) {
    const float* keys   = (const float*)d_in[0];
    const float* values = (const float*)d_in[1];
    const float* query  = (const float*)d_in[2];
    const float* k_bias = (const float*)d_in[3];
    const float* v_bias = (const float*)d_in[4];
    const float* sw     = (const float*)d_in[5];
    const float* sb     = (const float*)d_in[6];
    const float* gamma  = (const float*)d_in[7];
    const float* beta   = (const float*)d_in[8];
    float* out = (float*)d_out;

    // ws layout (floats): p[64][4112] | stats[64*8] float2 | partials[64][16][128]
    float* ws = (float*)d_ws;
    float* p = ws;
    float2* stats = (float2*)(ws + (long long)NG * SSTR);
    float* partials = ws + (long long)NG * SSTR + NG * NCK * 2;

    lqa_scores_kernel<<<dim3(NCK, NG), 256, 0, stream>>>(keys, k_bias, query, sw, sb, p, stats);
    lqa_av_kernel    <<<dim3(NC, NG),  256, 0, stream>>>(values, v_bias, p, stats, partials);
    lqa_ln_kernel    <<<BATCH,         256, 0, stream>>>(partials, gamma, beta, out);
}

// Round 5
// 264.607 us; speedup vs baseline: 1.0530x; 1.0530x over previous
//
#include <hip/hip_runtime.h>

// LearnedQueryAttention: B=8, L=4096, KD=512, ED=1024, H=8. All I/O fp32.
// Raw-reshape semantics: head h owns the contiguous flat slab
// f = h*(L+1)*(C/H) + row*(C/H) + d of per-batch [X_flat | bias]; only
// f >= L*C touches the bias token.
//
// dur_us includes harness reset traffic (512MB ws poison + ~200MB input
// restore); inputs are L3-hot at kernel time -> no nontemporal loads.
#define BATCH 8
#define LSEQ  4096
#define LP    4097
#define KDIM  512
#define EDIM  1024
#define NH    8
#define DK    64
#define DV    128
#define NG    64          // B*H groups
#define SSTR  4112        // padded per-group score stride (floats)
#define NCK   32          // score-stage chunks per group (8 blocks/CU)
#define RCK   129         // 32*129 = 4128 >= 4097
#define NC    32          // value-stage chunks per group
#define RC    129
#define LN_EPS 1e-5f

typedef float floatx4 __attribute__((ext_vector_type(4)));

// ---------------------------------------------------------------------------
// Kernel 1: t[g][row] = dot64(Q[h], Kcat) * w[h][row] + b[h][row], plus
// per-chunk online-softmax stats (m, z). Grid (32, 64), 256 thr.
// ---------------------------------------------------------------------------
__global__ __launch_bounds__(256) void lqa_scores_kernel(
    const float* __restrict__ keys, const float* __restrict__ k_bias,
    const float* __restrict__ query, const float* __restrict__ sw,
    const float* __restrict__ sb, float* __restrict__ p,
    float2* __restrict__ stats)
{
    const int chunk = blockIdx.x;            // 0..31
    const int g = blockIdx.y;                // 0..63
    const int b = g >> 3, h = g & 7;
    const int t = threadIdx.x;
    const int lane16 = t & 15;
    const int d0 = lane16 * 4;

    const floatx4 q = *reinterpret_cast<const floatx4*>(query + h * DK + d0);
    const float* kp = keys + (long long)b * (LSEQ * KDIM);
    const int fhead = h * (LP * DK);
    const int row0 = chunk * RCK;
    const int row_end = min(LP, row0 + RCK);
    float* prow = p + (long long)g * SSTR;
    const float* w = sw + h * LP;
    const float* bb = sb + h * LP;

    float mloc = -1e30f, zloc = 0.f;
    for (int row = row0 + (t >> 4); row < row_end; row += 16) {
        const int f = fhead + row * DK + d0;
        const floatx4 k = (f < LSEQ * KDIM)
            ? *reinterpret_cast<const floatx4*>(kp + f)
            : *reinterpret_cast<const floatx4*>(k_bias + (f - LSEQ * KDIM));
        float s = q.x * k.x + q.y * k.y + q.z * k.z + q.w * k.w;
        s += __shfl_xor(s, 1);
        s += __shfl_xor(s, 2);
        s += __shfl_xor(s, 4);
        s += __shfl_xor(s, 8);
        if (lane16 == 0) {
            const float tv = s * w[row] + bb[row];
            prow[row] = tv;
            if (tv > mloc) { zloc = zloc * __expf(mloc - tv) + 1.f; mloc = tv; }
            else            zloc += __expf(tv - mloc);
        }
    }

    __shared__ float mred[256], zred[256];
    mred[t] = mloc; zred[t] = zloc;
    for (int off = 128; off > 0; off >>= 1) {
        __syncthreads();
        if (t < off) {
            const float m1 = mred[t], z1 = zred[t];
            const float m2 = mred[t + off], z2 = zred[t + off];
            const float m = fmaxf(m1, m2);
            mred[t] = m;
            zred[t] = z1 * __expf(m1 - m) + z2 * __expf(m2 - m);
        }
    }
    if (t == 0) stats[g * NCK + chunk] = make_float2(mred[0], zred[0]);
}

// ---------------------------------------------------------------------------
// Kernel 2: combine chunk stats -> (m, Z); stage softmax weights
// exp(t-m)/Z for this value-chunk in LDS; accumulate A partials over Vcat.
// Grid (32, 64), 256 thr; 32 lanes per row (float4), 8 row subsets.
// Output partials are fully normalized.
// ---------------------------------------------------------------------------
__global__ __launch_bounds__(256) void lqa_av_kernel(
    const float* __restrict__ values, const float* __restrict__ v_bias,
    const float* __restrict__ p, const float2* __restrict__ stats,
    float* __restrict__ partials)
{
    const int chunk = blockIdx.x;            // 0..31
    const int g = blockIdx.y;                // 0..63
    const int b = g >> 3, h = g & 7;
    const int t = threadIdx.x;
    const int srow = t >> 5;                 // 0..7
    const int d0 = (t & 31) * 4;             // 0..124

    // global softmax stats (redundant per thread; 32 broadcast float2 loads)
    float m = -1e30f, Z = 0.f;
#pragma unroll
    for (int c = 0; c < NCK; ++c) {
        const float2 s = stats[g * NCK + c];
        const float mn = fmaxf(m, s.x);
        Z = Z * __expf(m - mn) + s.y * __expf(s.x - mn);
        m = mn;
    }
    const float rinv = 1.f / Z;

    const float* vp = values + (long long)b * (LSEQ * EDIM);
    const int fhead = h * (LP * DV);
    const float* prow = p + (long long)g * SSTR;
    const int row0 = chunk * RC;
    const int nrows = min(LP, row0 + RC) - row0;

    __shared__ float pw[RC];
    for (int r = t; r < nrows; r += 256)
        pw[r] = __expf(prow[row0 + r] - m) * rinv;
    __syncthreads();

    float acc[4] = {0.f, 0.f, 0.f, 0.f};
    for (int r = srow; r < nrows; r += 8) {
        const float wgt = pw[r];
        const int f = fhead + (row0 + r) * DV + d0;
        const floatx4 v = (f < LSEQ * EDIM)
            ? *reinterpret_cast<const floatx4*>(vp + f)
            : *reinterpret_cast<const floatx4*>(v_bias + (f - LSEQ * EDIM));
        acc[0] += wgt * v.x; acc[1] += wgt * v.y;
        acc[2] += wgt * v.z; acc[3] += wgt * v.w;
    }

    __shared__ float red[256 * 4];
#pragma unroll
    for (int j = 0; j < 4; ++j) red[t * 4 + j] = acc[j];
    for (int off = 128; off >= 32; off >>= 1) {
        __syncthreads();
        if (t < off) {
#pragma unroll
            for (int j = 0; j < 4; ++j) red[t * 4 + j] += red[(t + off) * 4 + j];
        }
    }
    __syncthreads();
    if (t < 32) {
        float* dst = partials + ((long long)(g * NC + chunk)) * DV + t * 4;
#pragma unroll
        for (int j = 0; j < 4; ++j) dst[j] = red[t * 4 + j];
    }
}

// ---------------------------------------------------------------------------
// Kernel 3: reduce chunk partials, LayerNorm over 1024 dims, gamma/beta.
// One block per batch.
// ---------------------------------------------------------------------------
__global__ __launch_bounds__(256) void lqa_ln_kernel(
    const float* __restrict__ partials, const float* __restrict__ gamma,
    const float* __restrict__ beta, float* __restrict__ out)
{
    const int b = blockIdx.x;
    const int t = threadIdx.x;
    __shared__ float r1[256], r2[256];

    float a[4];
    float s1 = 0.f, s2 = 0.f;
#pragma unroll
    for (int i = 0; i < 4; ++i) {
        const int e = t + i * 256;
        const int h = e >> 7, d = e & 127;
        const float* src = partials + ((long long)((b * NH + h) * NC)) * DV + d;
        float sum = 0.f;
#pragma unroll
        for (int c = 0; c < NC; ++c) sum += src[c * DV];
        a[i] = sum;
        s1 += sum;
        s2 += sum * sum;
    }
    r1[t] = s1; r2[t] = s2; __syncthreads();
    for (int off = 128; off > 0; off >>= 1) {
        if (t < off) { r1[t] += r1[t + off]; r2[t] += r2[t + off]; }
        __syncthreads();
    }
    const float mean = r1[0] * (1.0f / EDIM);
    const float var = r2[0] * (1.0f / EDIM) - mean * mean;
    const float inv = rsqrtf(var + LN_EPS);
#pragma unroll
    for (int i = 0; i < 4; ++i) {
        const int e = t + i * 256;
        out[(long long)b * EDIM + e] = (a[i] - mean) * inv * gamma[e] + beta[e];
    }
}

// ---------------------------------------------------------------------------
extern "C" void kernel_launch(void* const* d_in, const int* in_sizes, int n_in,
                              void* d_out, int out_size, void* d_ws, size_t ws_size,
                              hipStream_t stream) {
    const float* keys   = (const float*)d_in[0];
    const float* values = (const float*)d_in[1];
    const float* query  = (const float*)d_in[2];
    const float* k_bias = (const float*)d_in[3];
    const float* v_bias = (const float*)d_in[4];
    const float* sw     = (const float*)d_in[5];
    const float* sb     = (const float*)d_in[6];
    const float* gamma  = (const float*)d_in[7];
    const float* beta   = (const float*)d_in[8];
    float* out = (float*)d_out;

    // ws layout (floats): p[64][4112] | stats[64*32] float2 | partials[64][32][128]
    float* ws = (float*)d_ws;
    float* p = ws;
    float2* stats = (float2*)(ws + (long long)NG * SSTR);
    float* partials = ws + (long long)NG * SSTR + NG * NCK * 2;

    lqa_scores_kernel<<<dim3(NCK, NG), 256, 0, stream>>>(keys, k_bias, query, sw, sb, p, stats);
    lqa_av_kernel    <<<dim3(NC, NG),  256, 0, stream>>>(values, v_bias, p, stats, partials);
    lqa_ln_kernel    <<<BATCH,         256, 0, stream>>>(partials, gamma, beta, out);
}

// Round 6
// 258.443 us; speedup vs baseline: 1.0782x; 1.0239x over previous
//
#include <hip/hip_runtime.h>

// LearnedQueryAttention: B=8, L=4096, KD=512, ED=1024, H=8. All I/O fp32.
// Raw-reshape semantics: head h owns the contiguous flat slab
// f = h*(L+1)*(C/H) + row*(C/H) + d of per-batch [X_flat | bias]; only
// f >= L*C touches the bias token (head 7 rows 4089..4096).
//
// dur_us includes harness reset traffic (512MB ws poison ~78us + ~200MB input
// restore ~60us). Attackable share is the kernel pipeline; this round fuses
// scores+softmax+AV into one kernel (flash-style per-chunk, deferred
// normalization) and combine+LN into a second.
#define BATCH 8
#define LSEQ  4096
#define LP    4097
#define KDIM  512
#define EDIM  1024
#define NH    8
#define DK    64
#define DV    128
#define NG    64          // B*H groups
#define NC    32          // chunks per group
#define RC    129         // rows per chunk (32*129 = 4128 >= 4097)
#define LN_EPS 1e-5f

typedef float floatx4 __attribute__((ext_vector_type(4)));

// ---------------------------------------------------------------------------
// Kernel 1 (fused): per (group g, chunk): chunk-local attention partial.
//   Phase A: t[row] = dot64(Q[h], Kcat_row) * w[row] + b[row]  -> LDS
//            m_c = max(t), LDS t -> exp(t - m_c), z_c = sum
//   Phase B: acc_c[d] = sum_rows exp(t-m_c) * Vcat[row][d]
//   Writes acc_c (unnormalized) + stats (m_c, z_c). Grid (32, 64), 256 thr.
// ---------------------------------------------------------------------------
__global__ __launch_bounds__(256) void lqa_fused_kernel(
    const float* __restrict__ keys, const float* __restrict__ k_bias,
    const float* __restrict__ values, const float* __restrict__ v_bias,
    const float* __restrict__ query, const float* __restrict__ sw,
    const float* __restrict__ sb, float* __restrict__ partials,
    float2* __restrict__ stats)
{
    const int chunk = blockIdx.x;            // 0..31
    const int g = blockIdx.y;                // 0..63
    const int b = g >> 3, h = g & 7;
    const int t = threadIdx.x;
    const int lane16 = t & 15;
    const int d0k = lane16 * 4;

    const int row0 = chunk * RC;
    const int nrows = min(LP, row0 + RC) - row0;

    __shared__ float ts[RC];
    __shared__ float red1[256];
    __shared__ float red4[256 * 4];

    // ---- Phase A: scores for this chunk into LDS ----
    const floatx4 q = *reinterpret_cast<const floatx4*>(query + h * DK + d0k);
    const float* kp = keys + (long long)b * (LSEQ * KDIM);
    const int fheadk = h * (LP * DK);
    const float* w = sw + h * LP;
    const float* bb = sb + h * LP;

    float mloc = -1e30f;
    for (int r = (t >> 4); r < nrows; r += 16) {
        const int row = row0 + r;
        const int f = fheadk + row * DK + d0k;
        const floatx4 k = (f < LSEQ * KDIM)
            ? *reinterpret_cast<const floatx4*>(kp + f)
            : *reinterpret_cast<const floatx4*>(k_bias + (f - LSEQ * KDIM));
        float s = q.x * k.x + q.y * k.y + q.z * k.z + q.w * k.w;
        s += __shfl_xor(s, 1);
        s += __shfl_xor(s, 2);
        s += __shfl_xor(s, 4);
        s += __shfl_xor(s, 8);
        if (lane16 == 0) {
            const float tv = s * w[row] + bb[row];
            ts[r] = tv;
            mloc = fmaxf(mloc, tv);
        }
    }
    red1[t] = mloc;
    for (int off = 128; off > 0; off >>= 1) {
        __syncthreads();
        if (t < off) red1[t] = fmaxf(red1[t], red1[t + off]);
    }
    __syncthreads();
    const float mc = red1[0];
    __syncthreads();

    // convert ts -> exp(ts - mc), accumulate z
    float zloc = 0.f;
    for (int r = t; r < nrows; r += 256) {
        const float e = __expf(ts[r] - mc);
        ts[r] = e;
        zloc += e;
    }
    red1[t] = zloc;
    for (int off = 128; off > 0; off >>= 1) {
        __syncthreads();
        if (t < off) red1[t] += red1[t + off];
    }
    __syncthreads();
    const float zc = red1[0];

    // ---- Phase B: weighted V sweep ----
    const int srow = t >> 5;                 // 0..7
    const int d0v = (t & 31) * 4;            // 0..124
    const float* vp = values + (long long)b * (LSEQ * EDIM);
    const int fheadv = h * (LP * DV);

    float acc[4] = {0.f, 0.f, 0.f, 0.f};
    for (int r = srow; r < nrows; r += 8) {
        const float wgt = ts[r];
        const int f = fheadv + (row0 + r) * DV + d0v;
        const floatx4 v = (f < LSEQ * EDIM)
            ? *reinterpret_cast<const floatx4*>(vp + f)
            : *reinterpret_cast<const floatx4*>(v_bias + (f - LSEQ * EDIM));
        acc[0] += wgt * v.x; acc[1] += wgt * v.y;
        acc[2] += wgt * v.z; acc[3] += wgt * v.w;
    }

#pragma unroll
    for (int j = 0; j < 4; ++j) red4[t * 4 + j] = acc[j];
    for (int off = 128; off >= 32; off >>= 1) {
        __syncthreads();
        if (t < off) {
#pragma unroll
            for (int j = 0; j < 4; ++j) red4[t * 4 + j] += red4[(t + off) * 4 + j];
        }
    }
    __syncthreads();
    if (t < 32) {
        float* dst = partials + ((long long)(g * NC + chunk)) * DV + t * 4;
#pragma unroll
        for (int j = 0; j < 4; ++j) dst[j] = red4[t * 4 + j];
    }
    if (t == 0) stats[g * NC + chunk] = make_float2(mc, zc);
}

// ---------------------------------------------------------------------------
// Kernel 2 (fused): cross-chunk softmax combine + LayerNorm. One block/batch.
//   per head: m = max_c m_c, Z = sum_c z_c exp(m_c - m)
//   wc[h][c] = exp(m_c - m) / Z ;  A[e] = sum_c acc_c[d] * wc
//   then LayerNorm over 1024 dims, gamma/beta.
// ---------------------------------------------------------------------------
__global__ __launch_bounds__(256) void lqa_combine_ln_kernel(
    const float* __restrict__ partials, const float2* __restrict__ stats,
    const float* __restrict__ gamma, const float* __restrict__ beta,
    float* __restrict__ out)
{
    const int b = blockIdx.x;
    const int t = threadIdx.x;
    __shared__ float mh[NH], zh[NH];
    __shared__ float wc[NH * NC];            // 256 rescale weights
    __shared__ float r1[256], r2[256];

    // stage 1: per-head global (m, Z)
    if (t < NH) {
        const float2* st = stats + (b * NH + t) * NC;
        float m = -1e30f, Z = 0.f;
#pragma unroll
        for (int c = 0; c < NC; ++c) {
            const float2 s = st[c];
            const float mn = fmaxf(m, s.x);
            Z = Z * __expf(m - mn) + s.y * __expf(s.x - mn);
            m = mn;
        }
        mh[t] = m; zh[t] = Z;
    }
    __syncthreads();
    // stage 2: one rescale weight per thread (h = t>>5, c = t&31)
    {
        const int h = t >> 5, c = t & 31;
        const float2 s = stats[(b * NH + h) * NC + c];
        wc[t] = __expf(s.x - mh[h]) / zh[h];
    }
    __syncthreads();

    // stage 3: combine partials; each thread owns 4 embed dims
    float a[4];
    float s1 = 0.f, s2 = 0.f;
#pragma unroll
    for (int i = 0; i < 4; ++i) {
        const int e = t + i * 256;
        const int h = e >> 7, d = e & 127;
        const float* src = partials + ((long long)((b * NH + h) * NC)) * DV + d;
        const float* wr = wc + h * NC;
        float sum = 0.f;
#pragma unroll
        for (int c = 0; c < NC; ++c) sum += src[c * DV] * wr[c];
        a[i] = sum;
        s1 += sum;
        s2 += sum * sum;
    }
    r1[t] = s1; r2[t] = s2; __syncthreads();
    for (int off = 128; off > 0; off >>= 1) {
        if (t < off) { r1[t] += r1[t + off]; r2[t] += r2[t + off]; }
        __syncthreads();
    }
    const float mean = r1[0] * (1.0f / EDIM);
    const float var = r2[0] * (1.0f / EDIM) - mean * mean;
    const float inv = rsqrtf(var + LN_EPS);
#pragma unroll
    for (int i = 0; i < 4; ++i) {
        const int e = t + i * 256;
        out[(long long)b * EDIM + e] = (a[i] - mean) * inv * gamma[e] + beta[e];
    }
}

// ---------------------------------------------------------------------------
extern "C" void kernel_launch(void* const* d_in, const int* in_sizes, int n_in,
                              void* d_out, int out_size, void* d_ws, size_t ws_size,
                              hipStream_t stream) {
    const float* keys   = (const float*)d_in[0];
    const float* values = (const float*)d_in[1];
    const float* query  = (const float*)d_in[2];
    const float* k_bias = (const float*)d_in[3];
    const float* v_bias = (const float*)d_in[4];
    const float* sw     = (const float*)d_in[5];
    const float* sb     = (const float*)d_in[6];
    const float* gamma  = (const float*)d_in[7];
    const float* beta   = (const float*)d_in[8];
    float* out = (float*)d_out;

    // ws layout (floats): partials[64][32][128] | stats[64*32] float2 (~1.1 MB)
    float* ws = (float*)d_ws;
    float* partials = ws;
    float2* stats = (float2*)(ws + (long long)NG * NC * DV);

    lqa_fused_kernel<<<dim3(NC, NG), 256, 0, stream>>>(
        keys, k_bias, values, v_bias, query, sw, sb, partials, stats);
    lqa_combine_ln_kernel<<<BATCH, 256, 0, stream>>>(
        partials, stats, gamma, beta, out);
}